// Round 1
// 59.169 us; speedup vs baseline: 1.0250x; 1.0250x over previous
//
#include <hip/hip_runtime.h>

// SPU activation bound propagation (RIAI SPUTrainable), collapsed to elementwise.
//
// nal/nau are diagonal+bias matrices, so _substitute reduces to:
//   al = max(lw,0)*l + min(lw,0)*u + lb
//   au = max(uw,0)*u + min(uw,0)*l + ub
//
// This revision targets the latency wall: 65536 threads = 1024 waves on 1024
// SIMDs (exactly 1 wave/SIMD, zero TLP), so every dependency cycle is exposed.
//
//  (a) Bisection compare rewritten rcp-free. For c<0, t=e^c:
//        a = -t/(1+t)^2,  b = spu(c) - a*c
//        a*u + b >= req  <=>  t*(c - (u+1) - t) >= req*(1+t)^2   [(1+t)^2 > 0]
//      Dependency chain per iteration after v_exp: 4 ops (was exp+rcp+5).
//      The c+st / c-st candidates are computed before the exp, so the
//      loop-carried update after the compare is one v_cndmask.
//  (b) 12 bisection steps instead of 20. bl error = |l|*2^-12 ~ 1e-3 ->
//      output delta ~3e-3. Budget: 0.655 absolute; measured 0.03125 at 20.
//  (c) Fully branchless: ~55% of lanes are crossing, so every wave used to
//      execute all three divergent blocks serially. Computing neg/pos/secant
//      candidates unconditionally lets them schedule under the loop's exp
//      latency; final selection via cndmask.

__device__ __forceinline__ float frcp(float x) { return __builtin_amdgcn_rcpf(x); }

__global__ void __launch_bounds__(256)
spu_bounds_kernel(const float* __restrict__ lp, const float* __restrict__ up,
                  const float* __restrict__ tlr, const float* __restrict__ tur,
                  float2* __restrict__ out, int n) {
    int i = blockIdx.x * blockDim.x + threadIdx.x;
    if (i >= n) return;

    float l  = lp[i];
    float u  = up[i];
    // sigmoid(4x) = 1/(1+e^{-4x})
    float tl = frcp(1.0f + __expf(-4.0f * tlr[i]));
    float tu = frcp(1.0f + __expf(-4.0f * tur[i]));

    // ---- endpoint spu values, branchless (both exp forms always issued;
    // they pipeline and are off the critical path) ----
    float tL  = __expf(l);
    float ivL = frcp(1.0f + tL);
    float yl  = (l >= 0.0f) ? fmaf(l, l, -0.5f) : (-tL * ivL);
    float tU  = __expf(u);
    float ivU = frcp(1.0f + tU);
    float yu  = (u >= 0.0f) ? fmaf(u, u, -0.5f) : (-tU * ivU);

    // secant through endpoints
    float den = u - l;                       // > 0 (l < u guaranteed)
    float ea  = (yu - yl) * frcp(den + 1e-8f);
    float eb  = yl - l * ea;

    // ---- negative-branch upper tangent at cn = l + den*tu (cn<=0 there) ----
    float cn  = fmaf(den, tu, l);
    float tn  = __expf(cn);
    float ivn = frcp(1.0f + tn);
    float sn  = -tn * ivn;                   // spu(cn), neg form
    float an  = sn * ivn;                    // grad(cn) = -t/(1+t)^2
    float bn  = fmaf(-an, cn, sn);

    // ---- positive-branch lower tangent at cp = l + den*tl (cp>=0 there) ----
    float cp = fmaf(den, tl, l);
    float pa = 2.0f * cp;
    float pb = fmaf(-cp, cp, -0.5f);         // (cp^2-0.5) - 2cp*cp

    // ---- crossing branch (l < 0 < u) ----
    float req = fmaf(u, u, -0.5f);           // spu(u), u > 0 for crossing lanes
    float u1  = u + 1.0f;

    // bisection for leftmost covering tangent base, rcp-free compare.
    // interval [l, 0], midpoint walk: c1 = l/2, step w/4, w/8, ...
    float w  = -l;
    float c  = 0.5f * l;
    float st = 0.25f * w;
    float bl = l;
    #pragma unroll
    for (int it = 0; it < 12; ++it) {
        float cmu = c - u1;                  // issued before exp completes
        float cup = c + st;                  // candidate if covers
        float cdn = c - st;                  // candidate if not
        float t   = __expf(c);
        float q   = 1.0f + t;
        float lhs = t * (cmu - t);           // t*(c - u - 1 - t)
        float rhs = req * q * q;
        bool covers = lhs >= rhs;
        bl = covers ? c : bl;
        c  = covers ? cup : cdn;
        st *= 0.5f;
    }

    // final upper tangent at c2 = l + (bl-l)*tu  (<= 0 for crossing lanes)
    float c2  = fmaf(bl - l, tu, l);
    float t2  = __expf(c2);
    float iv2 = frcp(1.0f + t2);
    float s2  = -t2 * iv2;
    float ua  = s2 * iv2;
    float ub_ = fmaf(-ua, c2, s2);
    bool not_cov = fmaf(ua, u, ub_) <= req;
    float cuw = not_cov ? ea : ua;
    float cub = not_cov ? eb : ub_;

    // crossing lower bound
    float thr = -l * frcp(den);              // in (0,1) for crossing lanes
    // normal tangent at cl = l + den*tl (any sign), branchless grad/spu
    float cl  = fmaf(den, tl, l);
    float t3  = __expf(cl);
    float iv3 = frcp(1.0f + t3);
    float s3  = -t3 * iv3;
    float a3n = s3 * iv3;
    float a3  = (cl >= 0.0f) ? 2.0f * cl : a3n;
    float y3  = (cl >= 0.0f) ? fmaf(cl, cl, -0.5f) : s3;
    float nla = a3;
    float nlb = fmaf(-a3, cl, y3);
    // steep path: spu_shifted_over_x(l) * (1 - (tl/thr)^2), lb = -0.5
    bool  nrm_l = (l <= -1e-5f) || (l > 0.0f);
    float steep = nrm_l ? (yl + 0.5f) * frcp(l) : -0.25f;
    float r   = tl * frcp(thr);
    float wa  = steep * (1.0f - r * r);
    bool  isn = tl >= thr;
    float clw = isn ? nla : wa;
    float clb = isn ? nlb : -0.5f;

    // ---- branch select ----
    bool neg = (u <= 0.0f);
    bool pos = (l >= 0.0f);
    float lw = neg ? ea : (pos ? pa : clw);
    float lb = neg ? eb : (pos ? pb : clb);
    float uw = neg ? an : (pos ? ea : cuw);
    float ub = neg ? bn : (pos ? eb : cub);

    float al = fmaxf(lw, 0.0f) * l + fminf(lw, 0.0f) * u + lb;
    float au = fmaxf(uw, 0.0f) * u + fminf(uw, 0.0f) * l + ub;
    out[i] = make_float2(al, au);
}

extern "C" void kernel_launch(void* const* d_in, const int* in_sizes, int n_in,
                              void* d_out, int out_size, void* d_ws, size_t ws_size,
                              hipStream_t stream) {
    const float* l   = (const float*)d_in[0];
    const float* u   = (const float*)d_in[1];
    const float* tlr = (const float*)d_in[2];
    const float* tur = (const float*)d_in[3];
    float2* out = (float2*)d_out;
    int n = in_sizes[0];                 // 64*1024 = 65536
    int block = 256;
    int grid = (n + block - 1) / block;
    spu_bounds_kernel<<<grid, block, 0, stream>>>(l, u, tlr, tur, out, n);
}